// Round 1
// baseline (478.248 us; speedup 1.0000x reference)
//
#include <hip/hip_runtime.h>
#include <hip/hip_bf16.h>
#include <math.h>

// Problem constants
#define BB 512
#define NN 1000
#define CC 50
#define EE 128
#define HH 8
#define DD 16
#define NEGV (-1000000000.0f)

// Output offsets (floats)
#define O_AUG 0
#define O_GE  (512*512)            // 262144
#define O_G   (O_GE + 512*128)     // 327680
#define O_CP  (O_G + 512)          // 328192

// ---------------------------------------------------------------------------
// K0: combine weights.
//   W_qh[r][e] = 0.25 * sum_i Wq[r][i] * mWq[i][e]   (r < 384)   (1/sqrt(D)=0.25 folded)
//   W_kh[r][e] =        sum_i Wk[r][i] * mWk[i][e]   (r < 128)
//   W_vh[r][e] =        sum_i Wv[r][i] * mWv[i][e]   (r < 128)
// grid 640 blocks x 128 threads; block = one output row.
// ---------------------------------------------------------------------------
__global__ __launch_bounds__(128) void combine_w(
    const float* __restrict__ Wq, const float* __restrict__ Wk,
    const float* __restrict__ Wv,
    const float* __restrict__ mWq, const float* __restrict__ mWk,
    const float* __restrict__ mWv,
    float* __restrict__ Wqh, float* __restrict__ Wkh, float* __restrict__ Wvh)
{
    int rb = blockIdx.x;
    int e  = threadIdx.x;
    const float* A; const float* Bm; float* O; int r; float scale;
    if (rb < 384)      { A = Wq; Bm = mWq; O = Wqh; r = rb;       scale = 0.25f; }
    else if (rb < 512) { A = Wk; Bm = mWk; O = Wkh; r = rb - 384; scale = 1.0f; }
    else               { A = Wv; Bm = mWv; O = Wvh; r = rb - 512; scale = 1.0f; }
    float acc = 0.0f;
#pragma unroll 8
    for (int i = 0; i < 128; ++i)
        acc = fmaf(A[r * 128 + i], Bm[i * 128 + e], acc);
    O[r * 128 + e] = acc * scale;
}

// ---------------------------------------------------------------------------
// K1: fused dual masked mean over node_embeddings (the 262 MB read).
//   um[b][e] = sum_n (!mask[b][n])                ? node[b][n][e] : 0 / N
//   uc[b][e] = sum_n (!(mask[b][n]|cmask[b][n])) ? node[b][n][e] : 0 / N
// grid 512 blocks x 512 threads; float4 loads, 16 rows in flight.
// ---------------------------------------------------------------------------
__global__ __launch_bounds__(512) void reduce_nodes(
    const float* __restrict__ node, const int* __restrict__ mask,
    const int* __restrict__ cmask,
    float* __restrict__ um, float* __restrict__ uc)
{
    int b = blockIdx.x;
    int t = threadIdx.x;
    int v = t & 31;       // float4 column (0..31)
    int r = t >> 5;       // row in group of 16

    const float4* np = (const float4*)(node + (long)b * NN * EE);
    const int* mb  = mask  + (long)b * NN;
    const int* cb  = cmask + (long)b * NN;

    float4 a1 = make_float4(0.f, 0.f, 0.f, 0.f);
    float4 a2 = make_float4(0.f, 0.f, 0.f, 0.f);
    for (int n = r; n < NN; n += 16) {
        float4 x = np[n * 32 + v];
        int m1 = mb[n];
        int m2 = m1 | cb[n];
        if (!m1) { a1.x += x.x; a1.y += x.y; a1.z += x.z; a1.w += x.w; }
        if (!m2) { a2.x += x.x; a2.y += x.y; a2.z += x.z; a2.w += x.w; }
    }

    __shared__ float4 s1[16][32];
    __shared__ float4 s2[16][32];
    s1[r][v] = a1;
    s2[r][v] = a2;
    __syncthreads();
    if (t < 128) {
        const float* f1 = (const float*)s1;
        const float* f2 = (const float*)s2;
        float x1 = 0.f, x2 = 0.f;
#pragma unroll
        for (int rr = 0; rr < 16; ++rr) {
            x1 += f1[rr * 128 + t];
            x2 += f2[rr * 128 + t];
        }
        um[b * 128 + t] = x1 * (1.0f / (float)NN);
        uc[b * 128 + t] = x2 * (1.0f / (float)NN);
    }
}

// ---------------------------------------------------------------------------
// K2: per-batch fused attention + logits + argmax + output select.
// One block (256 threads) per batch element. cluster_embedding staged
// TRANSPOSED in LDS with row stride 57 (odd, gcd(25,32)=1 -> conflict-free
// for both i-consecutive and j-consecutive lane patterns).
// ---------------------------------------------------------------------------
__global__ __launch_bounds__(256) void fused_attn(
    const float* __restrict__ depot, const float* __restrict__ ce,
    const float* __restrict__ cur,   const float* __restrict__ augc,
    const float* __restrict__ cge,
    const int* __restrict__ isnew_p, const int* __restrict__ vmask,
    const int* __restrict__ guid,
    const float* __restrict__ Wks,   const float* __restrict__ Wo,
    const float* __restrict__ um,    const float* __restrict__ uc,
    const float* __restrict__ Wqh,   const float* __restrict__ Wkh,
    const float* __restrict__ Wvh,
    float* __restrict__ out)
{
    int b = blockIdx.x;
    int t = threadIdx.x;

    __shared__ float sT[128 * 57];   // ce^T: sT[i*57 + j] = ce[b][j][i]
    __shared__ float sctx[384];
    __shared__ float sqh[128];
    __shared__ float sU[8 * 128];    // U[h][i]
    __shared__ float sattn[8 * 64];  // scores -> attn, padded
    __shared__ float sp[8 * 128];    // p[h][i] = sum_j attn[h][j]*ce[j][i]
    __shared__ float sg[128];        // glimpse (h*16+d)
    __shared__ float sgo[128];       // glimpse @ Wo
    __shared__ float sr[128];        // Wks @ go
    __shared__ float slog[64];       // masked logits
    __shared__ int   svcm[64];
    __shared__ float s_m, s_lse;
    __shared__ int   s_arg;

    const float* ceb = ce + (long)b * CC * EE;

    // ---- stage ce transposed (global read coalesced: u-consecutive = i-consecutive)
    for (int u = t; u < CC * EE; u += 256) {
        int j = u >> 7, i = u & 127;
        sT[i * 57 + j] = ceb[u];
    }
    // ---- context vector
    if (t < 128) {
        sctx[t]       = um[b * 128 + t];
        sctx[128 + t] = cur[b * 128 + t];
        sctx[256 + t] = depot[b * 128 + t];
    }
    if (t < CC) svcm[t] = vmask[b * CC + t];
    __syncthreads();

    // ---- vcm[0] = !all(visited[1:])
    if (t == 0) {
        int allv = 1;
        for (int j = 1; j < CC; ++j) allv &= (svcm[j] != 0);
        svcm[0] = !allv;
    }
    // ---- qh = ctx @ W_qh (scale 1/sqrt(D) already folded)
    if (t < 128) {
        float acc = 0.f;
#pragma unroll 8
        for (int i = 0; i < 384; ++i)
            acc = fmaf(sctx[i], Wqh[i * 128 + t], acc);
        sqh[t] = acc;
    }
    __syncthreads();

    // ---- U[h][i] = sum_d W_kh[i][h*16+d] * qh[h*16+d]
    for (int u = t; u < 8 * 128; u += 256) {
        int h = u >> 7, i = u & 127;
        const float* wk = Wkh + i * 128 + h * 16;
        const float* q  = sqh + h * 16;
        float acc = 0.f;
#pragma unroll
        for (int d = 0; d < 16; ++d) acc = fmaf(wk[d], q[d], acc);
        sU[u] = acc;
    }
    __syncthreads();

    // ---- scores[h][j] = ce[j] . U[h]  (masked)
    for (int u = t; u < 8 * CC; u += 256) {
        int h = u / CC, j = u - h * CC;
        float acc = 0.f;
#pragma unroll 8
        for (int i = 0; i < 128; ++i)
            acc = fmaf(sT[i * 57 + j], sU[h * 128 + i], acc);
        sattn[h * 64 + j] = svcm[j] ? NEGV : acc;
    }
    __syncthreads();

    // ---- softmax per head (serial per head; C=50 is tiny)
    if (t < 8) {
        float m = -INFINITY;
        for (int j = 0; j < CC; ++j) m = fmaxf(m, sattn[t * 64 + j]);
        float s = 0.f;
        for (int j = 0; j < CC; ++j) s += expf(sattn[t * 64 + j] - m);
        float inv = 1.0f / s;
        for (int j = 0; j < CC; ++j)
            sattn[t * 64 + j] = expf(sattn[t * 64 + j] - m) * inv;
    }
    __syncthreads();

    // ---- p[h][i] = sum_j attn[h][j] * ce[j][i]
    for (int u = t; u < 8 * 128; u += 256) {
        int h = u >> 7, i = u & 127;
        float acc = 0.f;
#pragma unroll
        for (int j = 0; j < CC; ++j)
            acc = fmaf(sattn[h * 64 + j], sT[i * 57 + j], acc);
        sp[u] = acc;
    }
    __syncthreads();

    // ---- glimpse[h*16+d] = sum_i p[h][i] * W_vh[i][h*16+d]
    if (t < 128) {
        int h = t >> 4;
        float acc = 0.f;
#pragma unroll 8
        for (int i = 0; i < 128; ++i)
            acc = fmaf(sp[h * 128 + i], Wvh[i * 128 + t], acc);
        sg[t] = acc;
    }
    __syncthreads();

    // ---- go = glimpse @ mha_Wo
    if (t < 128) {
        float acc = 0.f;
#pragma unroll 8
        for (int i = 0; i < 128; ++i)
            acc = fmaf(sg[i], Wo[i * 128 + t], acc);
        sgo[t] = acc;
    }
    __syncthreads();

    // ---- r[i] = sum_e Wks[i][e] * go[e]
    if (t < 128) {
        float acc = 0.f;
#pragma unroll 8
        for (int e = 0; e < 128; ++e)
            acc = fmaf(Wks[t * 128 + e], sgo[e], acc);
        sr[t] = acc;
    }
    __syncthreads();

    // ---- logits (tanh-clipped, masked)
    if (t < CC) {
        float acc = 0.f;
#pragma unroll 8
        for (int i = 0; i < 128; ++i)
            acc = fmaf(sT[i * 57 + t], sr[i], acc);
        float l = tanhf(acc * 0.08838834764831845f) * 10.0f; // /sqrt(E), *CLIP
        slog[t] = svcm[t] ? NEGV : l;
    }
    __syncthreads();

    // ---- log_softmax stats + argmax (first occurrence, matches jnp.argmax)
    if (t == 0) {
        float m = -INFINITY;
        for (int j = 0; j < CC; ++j) m = fmaxf(m, slog[j]);
        float s = 0.f;
        for (int j = 0; j < CC; ++j) s += expf(slog[j] - m);
        int arg = 0; float best = slog[0];
        for (int j = 1; j < CC; ++j)
            if (slog[j] > best) { best = slog[j]; arg = j; }
        s_m = m; s_lse = logf(s); s_arg = arg;
    }
    __syncthreads();

    // ---- outputs
    bool nw = (isnew_p[b] != 0);
    int  g  = s_arg;
    if (t == 0) {
        out[O_G + b] = nw ? (float)g : (float)guid[b];
    }
    if (t < 128) {
        float nge = sT[t * 57 + g];  // cluster_embedding[b][g][t]
        const float* ac = augc + (long)b * 512;
        float a0 = nw ? uc[b * 128 + t]    : ac[t];
        float a1 = nw ? cur[b * 128 + t]   : ac[128 + t];
        float a2 = nw ? nge                : ac[256 + t];
        float a3 = nw ? depot[b * 128 + t] : ac[384 + t];
        float* ao = out + O_AUG + (long)b * 512;
        ao[t] = a0; ao[128 + t] = a1; ao[256 + t] = a2; ao[384 + t] = a3;
        out[O_GE + b * 128 + t] = nw ? nge : cge[b * 128 + t];
    }
    if (t < CC) {
        out[O_CP + b * CC + t] = nw ? ((slog[t] - s_m) - s_lse) : 0.0f;
    }
}

// ---------------------------------------------------------------------------
extern "C" void kernel_launch(void* const* d_in, const int* in_sizes, int n_in,
                              void* d_out, int out_size, void* d_ws, size_t ws_size,
                              hipStream_t stream) {
    const float* depot = (const float*)d_in[0];
    const float* ce    = (const float*)d_in[1];
    const float* cur   = (const float*)d_in[2];
    const float* node  = (const float*)d_in[3];
    const float* augc  = (const float*)d_in[4];
    const float* cge   = (const float*)d_in[5];
    const float* Wq    = (const float*)d_in[6];
    const float* Wk    = (const float*)d_in[7];
    const float* Wv    = (const float*)d_in[8];
    const float* Wks   = (const float*)d_in[9];
    const float* mWq   = (const float*)d_in[10];
    const float* mWk   = (const float*)d_in[11];
    const float* mWv   = (const float*)d_in[12];
    const float* mWo   = (const float*)d_in[13];
    const int*   isnew = (const int*)d_in[14];
    const int*   mask  = (const int*)d_in[15];
    const int*   cmask = (const int*)d_in[16];
    const int*   vmask = (const int*)d_in[17];
    const int*   guid  = (const int*)d_in[18];
    float* out = (float*)d_out;

    float* ws  = (float*)d_ws;
    float* um  = ws;                       // 512*128
    float* uc  = um  + 512 * 128;          // 512*128
    float* Wqh = uc  + 512 * 128;          // 384*128
    float* Wkh = Wqh + 384 * 128;          // 128*128
    float* Wvh = Wkh + 128 * 128;          // 128*128

    combine_w<<<640, 128, 0, stream>>>(Wq, Wk, Wv, mWq, mWk, mWv, Wqh, Wkh, Wvh);
    reduce_nodes<<<512, 512, 0, stream>>>(node, mask, cmask, um, uc);
    fused_attn<<<512, 256, 0, stream>>>(depot, ce, cur, augc, cge,
                                        isnew, vmask, guid, Wks, mWo,
                                        um, uc, Wqh, Wkh, Wvh, out);
}

// Round 2
// 417.284 us; speedup vs baseline: 1.1461x; 1.1461x over previous
//
#include <hip/hip_runtime.h>
#include <hip/hip_bf16.h>
#include <math.h>

// Problem constants
#define BB 512
#define NN 1000
#define CC 50
#define EE 128
#define HH 8
#define DD 16
#define NEGV (-1000000000.0f)

// Output offsets (floats)
#define O_AUG 0
#define O_GE  (512*512)            // 262144
#define O_G   (O_GE + 512*128)     // 327680
#define O_CP  (O_G + 512)          // 328192

typedef float vf4 __attribute__((ext_vector_type(4)));

// ---------------------------------------------------------------------------
// K0 "prep": blocks 0..511  -> fused dual masked mean over node_embeddings
//            blocks 512..559 -> combined weight products:
//              rows   0..383: Wqh = 0.25 * Wq @ mWq
//              rows 384..511: Wkh = Wk @ mWk
//              rows 512..639: Wvh = Wv @ mWv
//              rows 640..767: WoKs[g][i] = sum_e Wo[g][e] * Wks[i][e]
// 512 threads per block.
// ---------------------------------------------------------------------------
__global__ __launch_bounds__(512) void prep(
    const float* __restrict__ node, const int* __restrict__ mask,
    const int* __restrict__ cmask,
    const float* __restrict__ Wq, const float* __restrict__ Wk,
    const float* __restrict__ Wv, const float* __restrict__ Wks,
    const float* __restrict__ mWq, const float* __restrict__ mWk,
    const float* __restrict__ mWv, const float* __restrict__ Wo,
    float* __restrict__ um, float* __restrict__ uc,
    float* __restrict__ Wqh, float* __restrict__ Wkh,
    float* __restrict__ Wvh, float* __restrict__ WoKs)
{
    int t = threadIdx.x;
    if (blockIdx.x < 512) {
        // ------- dual masked reduction, one block per batch -------
        __shared__ float2 w[1000];       // per-row {keep1, keep2}
        __shared__ vf4 s1[16][32];
        __shared__ vf4 s2[16][32];
        int b = blockIdx.x;
        const int* mb = mask  + b * NN;
        const int* cb = cmask + b * NN;
        for (int n = t; n < NN; n += 512) {
            int m1 = mb[n];
            int m2 = m1 | cb[n];
            w[n] = make_float2(m1 ? 0.f : 1.f, m2 ? 0.f : 1.f);
        }
        __syncthreads();

        int v = t & 31, r = t >> 5;
        const vf4* np = (const vf4*)(node + (size_t)b * NN * EE);
        vf4 a1 = {0.f, 0.f, 0.f, 0.f};
        vf4 a2 = {0.f, 0.f, 0.f, 0.f};
        int n = r;
        for (; n + 48 < NN; n += 64) {
            vf4 x0 = __builtin_nontemporal_load(np + (n     ) * 32 + v);
            vf4 x1 = __builtin_nontemporal_load(np + (n + 16) * 32 + v);
            vf4 x2 = __builtin_nontemporal_load(np + (n + 32) * 32 + v);
            vf4 x3 = __builtin_nontemporal_load(np + (n + 48) * 32 + v);
            float2 w0 = w[n], w1 = w[n + 16], w2 = w[n + 32], w3 = w[n + 48];
            a1 += x0 * w0.x; a2 += x0 * w0.y;
            a1 += x1 * w1.x; a2 += x1 * w1.y;
            a1 += x2 * w2.x; a2 += x2 * w2.y;
            a1 += x3 * w3.x; a2 += x3 * w3.y;
        }
        for (; n < NN; n += 16) {
            vf4 x = __builtin_nontemporal_load(np + n * 32 + v);
            float2 ww = w[n];
            a1 += x * ww.x;
            a2 += x * ww.y;
        }
        s1[r][v] = a1;
        s2[r][v] = a2;
        __syncthreads();
        if (t < 128) {
            const float* f1 = (const float*)s1;
            const float* f2 = (const float*)s2;
            float x1 = 0.f, x2 = 0.f;
#pragma unroll
            for (int rr = 0; rr < 16; ++rr) {
                x1 += f1[rr * 128 + t];
                x2 += f2[rr * 128 + t];
            }
            um[b * 128 + t] = x1 * (1.0f / (float)NN);
            uc[b * 128 + t] = x2 * (1.0f / (float)NN);
        }
    } else {
        // ------- weight combine: 16 rows per block, 4 rows per 128-thread slice
        int wb = blockIdx.x - 512;       // 0..47
        int r0 = wb * 16;                // 0..767, matrix boundaries on 16s
        int sub = t >> 7;                // 0..3
        int e = t & 127;
        const float* A; const float* Bm; float* O; int rb; float sc; bool tb;
        if (r0 < 384)      { A = Wq; Bm = mWq; O = Wqh;  rb = r0;       sc = 0.25f; tb = false; }
        else if (r0 < 512) { A = Wk; Bm = mWk; O = Wkh;  rb = r0 - 384; sc = 1.0f;  tb = false; }
        else if (r0 < 640) { A = Wv; Bm = mWv; O = Wvh;  rb = r0 - 512; sc = 1.0f;  tb = false; }
        else               { A = Wo; Bm = Wks; O = WoKs; rb = r0 - 640; sc = 1.0f;  tb = true;  }
        float acc[4] = {0.f, 0.f, 0.f, 0.f};
        if (!tb) {
            for (int i = 0; i < 128; ++i) {
                float bv = Bm[i * 128 + e];
#pragma unroll
                for (int k = 0; k < 4; ++k)
                    acc[k] = fmaf(A[(rb + sub + 4 * k) * 128 + i], bv, acc[k]);
            }
        } else {
            for (int i = 0; i < 128; ++i) {
                float bv = Bm[e * 128 + i];   // Wks[e][i] (B transposed use)
#pragma unroll
                for (int k = 0; k < 4; ++k)
                    acc[k] = fmaf(A[(rb + sub + 4 * k) * 128 + i], bv, acc[k]);
            }
        }
#pragma unroll
        for (int k = 0; k < 4; ++k)
            O[(rb + sub + 4 * k) * 128 + e] = acc[k] * sc;
    }
}

// ---------------------------------------------------------------------------
// K1: per-batch fused attention + logits + argmax + output select.
// 256 threads per block, one block per batch. ce staged transposed with
// stride 57 (conflict-free for all access patterns used).
// ---------------------------------------------------------------------------
__global__ __launch_bounds__(256) void fused_attn(
    const float* __restrict__ depot, const float* __restrict__ ce,
    const float* __restrict__ cur,   const float* __restrict__ augc,
    const float* __restrict__ cge,
    const int* __restrict__ isnew_p, const int* __restrict__ vmask,
    const int* __restrict__ guid,
    const float* __restrict__ um,    const float* __restrict__ uc,
    const float* __restrict__ Wqh,   const float* __restrict__ Wkh,
    const float* __restrict__ Wvh,   const float* __restrict__ WoKs,
    float* __restrict__ out)
{
    int b = blockIdx.x;
    int t = threadIdx.x;

    __shared__ float sT[128 * 57];   // ce^T: sT[i*57 + j] = ce[b][j][i]
    __shared__ float sctx[384];
    __shared__ float sqh[128];
    __shared__ float spq[2][128];
    __shared__ float sU[8 * 128];    // U[h][i]
    __shared__ float sattn[8 * 64];  // scores -> attn
    __shared__ float sp[8 * 136];    // p[h][i], stride 136 breaks bank aliasing
    __shared__ float sg[128];        // glimpse
    __shared__ float sr[128];        // WoKs^T @ glimpse
    __shared__ float slog[64];       // masked logits
    __shared__ int   svcm[64];
    __shared__ float s_m, s_lse;
    __shared__ int   s_arg;

    const float* ceb = ce + (size_t)b * CC * EE;

    for (int u = t; u < CC * EE; u += 256) {
        int j = u >> 7, i = u & 127;
        sT[i * 57 + j] = ceb[u];
    }
    if (t < 128) {
        sctx[t]       = um[b * 128 + t];
        sctx[128 + t] = cur[b * 128 + t];
        sctx[256 + t] = depot[b * 128 + t];
    }
    if (t < 64) svcm[t] = (t < CC) ? vmask[b * CC + t] : 1;
    __syncthreads();

    // vcm[0] = !all(visited[1:]) — wave-0 ballot
    if (t < 64) {
        int pred = (t >= 1 && t < CC) ? (svcm[t] != 0) : 1;
        int allv = __all(pred);
        if (t == 0) svcm[0] = !allv;
    }
    // qh = ctx @ W_qh, split K=384 across 2 threads/output
    {
        int e = t & 127, half = t >> 7;
        int i0 = half * 192;
        float acc = 0.f;
#pragma unroll 8
        for (int i = 0; i < 192; ++i)
            acc = fmaf(sctx[i0 + i], Wqh[(i0 + i) * 128 + e], acc);
        spq[half][e] = acc;
    }
    __syncthreads();
    if (t < 128) sqh[t] = spq[0][t] + spq[1][t];
    __syncthreads();

    // U[h][i] = sum_d W_kh[i][h*16+d] * qh[h*16+d]
    for (int u = t; u < 8 * 128; u += 256) {
        int h = u >> 7, i = u & 127;
        const float* wk = Wkh + i * 128 + h * 16;
        const float* q  = sqh + h * 16;
        float acc = 0.f;
#pragma unroll
        for (int d = 0; d < 16; ++d) acc = fmaf(wk[d], q[d], acc);
        sU[u] = acc;
    }
    __syncthreads();

    // scores[h][j] = ce[j] . U[h]  (masked)
    for (int u = t; u < 8 * CC; u += 256) {
        int h = u / CC, j = u - h * CC;
        float acc = 0.f;
#pragma unroll 8
        for (int i = 0; i < 128; ++i)
            acc = fmaf(sT[i * 57 + j], sU[h * 128 + i], acc);
        sattn[h * 64 + j] = svcm[j] ? NEGV : acc;
    }
    __syncthreads();

    // softmax: 32 lanes per head, shuffle reductions
    {
        int h = t >> 5, l = t & 31;
        float s0 = sattn[h * 64 + l];
        float s1v = (l < CC - 32) ? sattn[h * 64 + l + 32] : -INFINITY;
        float m = fmaxf(s0, s1v);
#pragma unroll
        for (int off = 16; off >= 1; off >>= 1)
            m = fmaxf(m, __shfl_xor(m, off, 32));
        float e0 = expf(s0 - m);
        float e1 = (l < CC - 32) ? expf(s1v - m) : 0.f;
        float ssum = e0 + e1;
#pragma unroll
        for (int off = 16; off >= 1; off >>= 1)
            ssum += __shfl_xor(ssum, off, 32);
        float inv = 1.0f / ssum;
        sattn[h * 64 + l] = e0 * inv;
        if (l < CC - 32) sattn[h * 64 + l + 32] = e1 * inv;
    }
    __syncthreads();

    // p[h][i] = sum_j attn[h][j] * ce[j][i]
    for (int u = t; u < 8 * 128; u += 256) {
        int h = u >> 7, i = u & 127;
        float acc = 0.f;
#pragma unroll
        for (int j = 0; j < CC; ++j)
            acc = fmaf(sattn[h * 64 + j], sT[i * 57 + j], acc);
        sp[h * 136 + i] = acc;
    }
    __syncthreads();

    // glimpse[h*16+d] = sum_i p[h][i] * W_vh[i][h*16+d]
    if (t < 128) {
        int h = t >> 4;
        float acc = 0.f;
#pragma unroll 8
        for (int i = 0; i < 128; ++i)
            acc = fmaf(sp[h * 136 + i], Wvh[i * 128 + t], acc);
        sg[t] = acc;
    }
    __syncthreads();

    // r[i] = sum_g glimpse[g] * WoKs[g][i]   (Wo and Wks folded; coalesced)
    if (t < 128) {
        float acc = 0.f;
#pragma unroll 8
        for (int g = 0; g < 128; ++g)
            acc = fmaf(sg[g], WoKs[g * 128 + t], acc);
        sr[t] = acc;
    }
    __syncthreads();

    // logits (tanh-clipped, masked)
    if (t < 64) {
        if (t < CC) {
            float acc = 0.f;
#pragma unroll 8
            for (int i = 0; i < 128; ++i)
                acc = fmaf(sT[i * 57 + t], sr[i], acc);
            float l = tanhf(acc * 0.08838834764831845f) * 10.0f; // /sqrt(E), *CLIP
            slog[t] = svcm[t] ? NEGV : l;
        } else {
            slog[t] = NEGV;
        }
    }
    __syncthreads();

    // lse + argmax on wave 0 (first-occurrence tie-break = min index)
    if (t < 64) {
        float val = (t < CC) ? slog[t] : -INFINITY;
        int idx = t;
#pragma unroll
        for (int off = 32; off >= 1; off >>= 1) {
            float ov = __shfl_xor(val, off, 64);
            int   oi = __shfl_xor(idx, off, 64);
            if (ov > val || (ov == val && oi < idx)) { val = ov; idx = oi; }
        }
        float m = val;
        float ex = (t < CC) ? expf(slog[t] - m) : 0.f;
#pragma unroll
        for (int off = 32; off >= 1; off >>= 1)
            ex += __shfl_xor(ex, off, 64);
        if (t == 0) { s_m = m; s_arg = idx; s_lse = logf(ex); }
    }
    __syncthreads();

    // outputs
    bool nw = (isnew_p[b] != 0);
    int  g  = s_arg;
    if (t == 0) {
        out[O_G + b] = nw ? (float)g : (float)guid[b];
    }
    if (t < 128) {
        float nge = sT[t * 57 + g];  // cluster_embedding[b][g][t]
        const float* ac = augc + (size_t)b * 512;
        float a0 = nw ? uc[b * 128 + t]    : ac[t];
        float a1 = nw ? cur[b * 128 + t]   : ac[128 + t];
        float a2 = nw ? nge                : ac[256 + t];
        float a3 = nw ? depot[b * 128 + t] : ac[384 + t];
        float* ao = out + O_AUG + (size_t)b * 512;
        ao[t] = a0; ao[128 + t] = a1; ao[256 + t] = a2; ao[384 + t] = a3;
        out[O_GE + b * 128 + t] = nw ? nge : cge[b * 128 + t];
    }
    if (t < CC) {
        out[O_CP + b * CC + t] = nw ? ((slog[t] - s_m) - s_lse) : 0.0f;
    }
}

// ---------------------------------------------------------------------------
extern "C" void kernel_launch(void* const* d_in, const int* in_sizes, int n_in,
                              void* d_out, int out_size, void* d_ws, size_t ws_size,
                              hipStream_t stream) {
    const float* depot = (const float*)d_in[0];
    const float* ce    = (const float*)d_in[1];
    const float* cur   = (const float*)d_in[2];
    const float* node  = (const float*)d_in[3];
    const float* augc  = (const float*)d_in[4];
    const float* cge   = (const float*)d_in[5];
    const float* Wq    = (const float*)d_in[6];
    const float* Wk    = (const float*)d_in[7];
    const float* Wv    = (const float*)d_in[8];
    const float* Wks   = (const float*)d_in[9];
    const float* mWq   = (const float*)d_in[10];
    const float* mWk   = (const float*)d_in[11];
    const float* mWv   = (const float*)d_in[12];
    const float* mWo   = (const float*)d_in[13];
    const int*   isnew = (const int*)d_in[14];
    const int*   mask  = (const int*)d_in[15];
    const int*   cmask = (const int*)d_in[16];
    const int*   vmask = (const int*)d_in[17];
    const int*   guid  = (const int*)d_in[18];
    float* out = (float*)d_out;

    float* ws   = (float*)d_ws;
    float* um   = ws;                       // 512*128
    float* uc   = um   + 512 * 128;         // 512*128
    float* Wqh  = uc   + 512 * 128;         // 384*128
    float* Wkh  = Wqh  + 384 * 128;         // 128*128
    float* Wvh  = Wkh  + 128 * 128;         // 128*128
    float* WoKs = Wvh  + 128 * 128;         // 128*128

    prep<<<560, 512, 0, stream>>>(node, mask, cmask,
                                  Wq, Wk, Wv, Wks, mWq, mWk, mWv, mWo,
                                  um, uc, Wqh, Wkh, Wvh, WoKs);
    fused_attn<<<512, 256, 0, stream>>>(depot, ce, cur, augc, cge,
                                        isnew, vmask, guid,
                                        um, uc, Wqh, Wkh, Wvh, WoKs, out);
}

// Round 3
// 414.626 us; speedup vs baseline: 1.1534x; 1.0064x over previous
//
#include <hip/hip_runtime.h>
#include <hip/hip_bf16.h>
#include <math.h>

// Problem constants
#define BB 512
#define NN 1000
#define CC 50
#define EE 128
#define HH 8
#define DD 16
#define NEGV (-1000000000.0f)

// Output offsets (floats)
#define O_AUG 0
#define O_GE  (512*512)            // 262144
#define O_G   (O_GE + 512*128)     // 327680
#define O_CP  (O_G + 512)          // 328192

typedef float vf4 __attribute__((ext_vector_type(4)));

// ---------------------------------------------------------------------------
// K0 "wprep": combined weight products (48 blocks x 512 threads, 16 rows/blk)
//   rows   0..383: Wqh = 0.25 * Wq @ mWq      (1/sqrt(D) folded)
//   rows 384..511: Wkh = Wk @ mWk
//   rows 512..639: Wvh = Wv @ mWv
//   rows 640..767: WoKs[g][i] = sum_e Wo[g][e] * Wks[i][e]
// ---------------------------------------------------------------------------
__global__ __launch_bounds__(512) void wprep(
    const float* __restrict__ Wq, const float* __restrict__ Wk,
    const float* __restrict__ Wv, const float* __restrict__ Wks,
    const float* __restrict__ mWq, const float* __restrict__ mWk,
    const float* __restrict__ mWv, const float* __restrict__ Wo,
    float* __restrict__ Wqh, float* __restrict__ Wkh,
    float* __restrict__ Wvh, float* __restrict__ WoKs)
{
    int t   = threadIdx.x;
    int r0  = blockIdx.x * 16;       // matrix boundaries land on multiples of 16
    int sub = t >> 7;                // 0..3
    int e   = t & 127;
    const float* A; const float* Bm; float* O; int rb; float sc; bool tb;
    if (r0 < 384)      { A = Wq; Bm = mWq; O = Wqh;  rb = r0;       sc = 0.25f; tb = false; }
    else if (r0 < 512) { A = Wk; Bm = mWk; O = Wkh;  rb = r0 - 384; sc = 1.0f;  tb = false; }
    else if (r0 < 640) { A = Wv; Bm = mWv; O = Wvh;  rb = r0 - 512; sc = 1.0f;  tb = false; }
    else               { A = Wo; Bm = Wks; O = WoKs; rb = r0 - 640; sc = 1.0f;  tb = true;  }
    float acc[4] = {0.f, 0.f, 0.f, 0.f};
    if (!tb) {
        for (int i = 0; i < 128; ++i) {
            float bv = Bm[i * 128 + e];
#pragma unroll
            for (int k = 0; k < 4; ++k)
                acc[k] = fmaf(A[(rb + sub + 4 * k) * 128 + i], bv, acc[k]);
        }
    } else {
        for (int i = 0; i < 128; ++i) {
            float bv = Bm[e * 128 + i];   // Wks used transposed
#pragma unroll
            for (int k = 0; k < 4; ++k)
                acc[k] = fmaf(A[(rb + sub + 4 * k) * 128 + i], bv, acc[k]);
        }
    }
#pragma unroll
    for (int k = 0; k < 4; ++k)
        O[(rb + sub + 4 * k) * 128 + e] = acc[k] * sc;
}

// ---------------------------------------------------------------------------
// K1 "mega": one block (512 threads) per batch element.
//   Phase 1: stage masks->weights, ce^T (stride 57), vcm, cur/depot context
//   Phase 2: dual masked mean over node_embeddings (262 MB stream, BW-bound)
//   Phase 3: rank-1 attention + logits + argmax + output select, all in LDS
// ---------------------------------------------------------------------------
__global__ __launch_bounds__(512) void mega(
    const float* __restrict__ node,  const int* __restrict__ mask,
    const int* __restrict__ cmask,
    const float* __restrict__ depot, const float* __restrict__ ce,
    const float* __restrict__ cur,   const float* __restrict__ augc,
    const float* __restrict__ cge,
    const int* __restrict__ isnew_p, const int* __restrict__ vmask,
    const int* __restrict__ guid,
    const float* __restrict__ Wqh,   const float* __restrict__ Wkh,
    const float* __restrict__ Wvh,   const float* __restrict__ WoKs,
    float* __restrict__ out)
{
    int b = blockIdx.x;
    int t = threadIdx.x;

    __shared__ float  sT[128 * 57];   // ce^T: sT[i*57+j] = ce[b][j][i]
    __shared__ float2 w[1000];        // per-row {keep1, keep2}
    __shared__ vf4    s1[16][32];
    __shared__ vf4    s2[16][32];
    __shared__ float  sctx[384];      // [um | cur | depot]
    __shared__ float  suc[128];       // uc
    __shared__ float  spq[4][128];
    __shared__ float  sqh[128];
    __shared__ float  sU[8 * 128];
    __shared__ float  sattn[8 * 64];
    __shared__ float  sp[8 * 136];
    __shared__ float  sg[128];
    __shared__ float  sr[128];
    __shared__ float  slog[64];
    __shared__ int    svcm[64];
    __shared__ float  s_m, s_lse;
    __shared__ int    s_arg;

    // ---------------- Phase 1: staging ----------------
    const int* mb = mask  + b * NN;
    const int* cb = cmask + b * NN;
    for (int n = t; n < NN; n += 512) {
        int m1 = mb[n];
        int m2 = m1 | cb[n];
        w[n] = make_float2(m1 ? 0.f : 1.f, m2 ? 0.f : 1.f);
    }
    const float* ceb = ce + (size_t)b * CC * EE;
    for (int u = t; u < CC * EE; u += 512) {
        int j = u >> 7, i = u & 127;
        sT[i * 57 + j] = ceb[u];
    }
    if (t >= 128 && t < 256) {
        int e = t - 128;
        sctx[128 + e] = cur[b * 128 + e];
        sctx[256 + e] = depot[b * 128 + e];
    }
    if (t >= 256 && t < 320) {
        int j = t - 256;
        svcm[j] = (j < CC) ? vmask[b * CC + j] : 1;
    }
    __syncthreads();

    // vcm[0] = !all(visited[1:]) — wave-0 ballot
    if (t < 64) {
        int pred = (t >= 1 && t < CC) ? (svcm[t] != 0) : 1;
        int allv = __all(pred);
        if (t == 0) svcm[0] = !allv;
    }

    // ---------------- Phase 2: dual masked reduction ----------------
    {
        int v = t & 31, r = t >> 5;   // 16 rows in flight, 2 rows per wave
        const vf4* np = (const vf4*)(node + (size_t)b * NN * EE);
        vf4 a1 = {0.f, 0.f, 0.f, 0.f};
        vf4 a2 = {0.f, 0.f, 0.f, 0.f};
        int n = r;
        for (; n + 48 < NN; n += 64) {
            vf4 x0 = __builtin_nontemporal_load(np + (n     ) * 32 + v);
            vf4 x1 = __builtin_nontemporal_load(np + (n + 16) * 32 + v);
            vf4 x2 = __builtin_nontemporal_load(np + (n + 32) * 32 + v);
            vf4 x3 = __builtin_nontemporal_load(np + (n + 48) * 32 + v);
            float2 w0 = w[n], w1 = w[n + 16], w2 = w[n + 32], w3 = w[n + 48];
            a1 += x0 * w0.x; a2 += x0 * w0.y;
            a1 += x1 * w1.x; a2 += x1 * w1.y;
            a1 += x2 * w2.x; a2 += x2 * w2.y;
            a1 += x3 * w3.x; a2 += x3 * w3.y;
        }
        for (; n < NN; n += 16) {
            vf4 x = __builtin_nontemporal_load(np + n * 32 + v);
            float2 ww = w[n];
            a1 += x * ww.x;
            a2 += x * ww.y;
        }
        s1[r][v] = a1;
        s2[r][v] = a2;
    }
    __syncthreads();
    if (t < 128) {
        const float* f1 = (const float*)s1;
        const float* f2 = (const float*)s2;
        float x1 = 0.f, x2 = 0.f;
#pragma unroll
        for (int rr = 0; rr < 16; ++rr) {
            x1 += f1[rr * 128 + t];
            x2 += f2[rr * 128 + t];
        }
        sctx[t] = x1 * (1.0f / (float)NN);   // um -> context slot 0
        suc[t]  = x2 * (1.0f / (float)NN);   // uc
    }
    __syncthreads();

    // ---------------- Phase 3: attention / logits / outputs ----------------
    // qh = ctx @ W_qh, K=384 split across 4 threads per output column
    {
        int e = t & 127, q4 = t >> 7;   // 0..3
        int i0 = q4 * 96;
        float acc = 0.f;
#pragma unroll 8
        for (int i = 0; i < 96; ++i)
            acc = fmaf(sctx[i0 + i], Wqh[(i0 + i) * 128 + e], acc);
        spq[q4][e] = acc;
    }
    __syncthreads();
    if (t < 128) sqh[t] = (spq[0][t] + spq[1][t]) + (spq[2][t] + spq[3][t]);
    __syncthreads();

    // U[h][i] = sum_d W_kh[i][h*16+d] * qh[h*16+d]
    for (int u = t; u < 8 * 128; u += 512) {
        int h = u >> 7, i = u & 127;
        const float* wk = Wkh + i * 128 + h * 16;
        const float* q  = sqh + h * 16;
        float acc = 0.f;
#pragma unroll
        for (int d = 0; d < 16; ++d) acc = fmaf(wk[d], q[d], acc);
        sU[u] = acc;
    }
    __syncthreads();

    // scores[h][j] = ce[j] . U[h]  (masked)
    if (t < 8 * CC) {
        int h = t / CC, j = t - h * CC;
        float acc = 0.f;
#pragma unroll 8
        for (int i = 0; i < 128; ++i)
            acc = fmaf(sT[i * 57 + j], sU[h * 128 + i], acc);
        sattn[h * 64 + j] = svcm[j] ? NEGV : acc;
    }
    __syncthreads();

    // softmax: 32 lanes per head, shuffle reductions
    if (t < 256) {
        int h = t >> 5, l = t & 31;
        float s0  = sattn[h * 64 + l];
        float s1v = (l < CC - 32) ? sattn[h * 64 + l + 32] : -INFINITY;
        float m = fmaxf(s0, s1v);
#pragma unroll
        for (int off = 16; off >= 1; off >>= 1)
            m = fmaxf(m, __shfl_xor(m, off, 32));
        float e0 = expf(s0 - m);
        float e1 = (l < CC - 32) ? expf(s1v - m) : 0.f;
        float ssum = e0 + e1;
#pragma unroll
        for (int off = 16; off >= 1; off >>= 1)
            ssum += __shfl_xor(ssum, off, 32);
        float inv = 1.0f / ssum;
        sattn[h * 64 + l] = e0 * inv;
        if (l < CC - 32) sattn[h * 64 + l + 32] = e1 * inv;
    }
    __syncthreads();

    // p[h][i] = sum_j attn[h][j] * ce[j][i]
    for (int u = t; u < 8 * 128; u += 512) {
        int h = u >> 7, i = u & 127;
        float acc = 0.f;
#pragma unroll
        for (int j = 0; j < CC; ++j)
            acc = fmaf(sattn[h * 64 + j], sT[i * 57 + j], acc);
        sp[h * 136 + i] = acc;
    }
    __syncthreads();

    // glimpse[h*16+d] = sum_i p[h][i] * W_vh[i][h*16+d]
    if (t < 128) {
        int h = t >> 4;
        float acc = 0.f;
#pragma unroll 8
        for (int i = 0; i < 128; ++i)
            acc = fmaf(sp[h * 136 + i], Wvh[i * 128 + t], acc);
        sg[t] = acc;
    }
    __syncthreads();

    // r[i] = sum_g glimpse[g] * WoKs[g][i]   (Wo,Wks folded; coalesced)
    if (t < 128) {
        float acc = 0.f;
#pragma unroll 8
        for (int g = 0; g < 128; ++g)
            acc = fmaf(sg[g], WoKs[g * 128 + t], acc);
        sr[t] = acc;
    }
    __syncthreads();

    // logits (tanh-clipped, masked)
    if (t < 64) {
        if (t < CC) {
            float acc = 0.f;
#pragma unroll 8
            for (int i = 0; i < 128; ++i)
                acc = fmaf(sT[i * 57 + t], sr[i], acc);
            float l = tanhf(acc * 0.08838834764831845f) * 10.0f; // /sqrt(E)*CLIP
            slog[t] = svcm[t] ? NEGV : l;
        } else {
            slog[t] = NEGV;
        }
    }
    __syncthreads();

    // lse + argmax on wave 0 (first-occurrence tie-break = min index)
    if (t < 64) {
        float val = (t < CC) ? slog[t] : -INFINITY;
        int idx = t;
#pragma unroll
        for (int off = 32; off >= 1; off >>= 1) {
            float ov = __shfl_xor(val, off, 64);
            int   oi = __shfl_xor(idx, off, 64);
            if (ov > val || (ov == val && oi < idx)) { val = ov; idx = oi; }
        }
        float m = val;
        float ex = (t < CC) ? expf(slog[t] - m) : 0.f;
#pragma unroll
        for (int off = 32; off >= 1; off >>= 1)
            ex += __shfl_xor(ex, off, 64);
        if (t == 0) { s_m = m; s_arg = idx; s_lse = logf(ex); }
    }
    __syncthreads();

    // outputs
    bool nw = (isnew_p[b] != 0);
    int  g  = s_arg;
    if (t == 0) {
        out[O_G + b] = nw ? (float)g : (float)guid[b];
    }
    if (t < 128) {
        float nge = sT[t * 57 + g];  // cluster_embedding[b][g][t]
        const float* ac = augc + (size_t)b * 512;
        float a0 = nw ? suc[t]             : ac[t];
        float a1 = nw ? sctx[128 + t]      : ac[128 + t];
        float a2 = nw ? nge                : ac[256 + t];
        float a3 = nw ? sctx[256 + t]      : ac[384 + t];
        float* ao = out + O_AUG + (size_t)b * 512;
        ao[t] = a0; ao[128 + t] = a1; ao[256 + t] = a2; ao[384 + t] = a3;
        out[O_GE + b * 128 + t] = nw ? nge : cge[b * 128 + t];
    }
    if (t >= 128 && t < 128 + CC) {
        int j = t - 128;
        out[O_CP + b * CC + j] = nw ? ((slog[j] - s_m) - s_lse) : 0.0f;
    }
}

// ---------------------------------------------------------------------------
extern "C" void kernel_launch(void* const* d_in, const int* in_sizes, int n_in,
                              void* d_out, int out_size, void* d_ws, size_t ws_size,
                              hipStream_t stream) {
    const float* depot = (const float*)d_in[0];
    const float* ce    = (const float*)d_in[1];
    const float* cur   = (const float*)d_in[2];
    const float* node  = (const float*)d_in[3];
    const float* augc  = (const float*)d_in[4];
    const float* cge   = (const float*)d_in[5];
    const float* Wq    = (const float*)d_in[6];
    const float* Wk    = (const float*)d_in[7];
    const float* Wv    = (const float*)d_in[8];
    const float* Wks   = (const float*)d_in[9];
    const float* mWq   = (const float*)d_in[10];
    const float* mWk   = (const float*)d_in[11];
    const float* mWv   = (const float*)d_in[12];
    const float* mWo   = (const float*)d_in[13];
    const int*   isnew = (const int*)d_in[14];
    const int*   mask  = (const int*)d_in[15];
    const int*   cmask = (const int*)d_in[16];
    const int*   vmask = (const int*)d_in[17];
    const int*   guid  = (const int*)d_in[18];
    float* out = (float*)d_out;

    float* ws   = (float*)d_ws;
    float* Wqh  = ws;                       // 384*128
    float* Wkh  = Wqh  + 384 * 128;         // 128*128
    float* Wvh  = Wkh  + 128 * 128;         // 128*128
    float* WoKs = Wvh  + 128 * 128;         // 128*128

    wprep<<<48, 512, 0, stream>>>(Wq, Wk, Wv, Wks, mWq, mWk, mWv, mWo,
                                  Wqh, Wkh, Wvh, WoKs);
    mega<<<512, 512, 0, stream>>>(node, mask, cmask,
                                  depot, ce, cur, augc, cge,
                                  isnew, vmask, guid,
                                  Wqh, Wkh, Wvh, WoKs, out);
}